// Round 7
// baseline (80.223 us; speedup 1.0000x reference)
//
#include <hip/hip_runtime.h>

#define BB 64
#define CC 3
#define HH 224
#define WW 224
#define KK 37
#define PP 18
#define PLANE (HH*WW)

#define BM 32            // output rows per block; 224 = 7*32, no tail
#define BROWS 68         // BM + KK - 1
#define BSTR 264         // shorts; 132 dw == 4 mod 8 -> conflict-free; rows 16B-aligned
#define FRAGS 2560       // shorts per (slab,ky): 5q x 2hi x 32ln x 8j
#define NTT (8*CC*KK)    // 888 fragment blocks

typedef __attribute__((ext_vector_type(8)))  __bf16 bf16x8;
typedef __attribute__((ext_vector_type(16))) float  f32x16;

__device__ __forceinline__ unsigned short f2bf(float f) {
    unsigned int u = __float_as_uint(f);
    return (unsigned short)((u + 0x7FFFu + ((u >> 16) & 1u)) >> 16);   // RNE
}
__device__ __forceinline__ float bf2f(unsigned short h) {
    return __uint_as_float(((unsigned int)h) << 16);
}

// frag[s][q][hi][ln][j] = w[ky][16q+8hi+j - ln] (0 outside band); 1KB per wave-load
__global__ __launch_bounds__(256) void build_frags(
    const float* __restrict__ psf, unsigned short* __restrict__ tt)
{
    const int s = blockIdx.x;                // (p*3+c)*37 + ky
    const int ky = s % KK;
    const int pc = s / KK;
    const int p = pc / CC, c = pc - (pc / CC) * CC;
    const float* wrow = psf + (size_t)(((p*5 + 2)*CC + c)*KK + ky) * KK;
    unsigned short* dst = tt + (size_t)s * FRAGS;
    for (int e = threadIdx.x; e < FRAGS; e += 256) {
        int j = e & 7, ln = (e >> 3) & 31, hi = (e >> 8) & 1, q = e >> 9;
        int kx = 16*q + 8*hi + j - ln;
        dst[e] = (kx >= 0 && kx < KK) ? f2bf(wrow[kx]) : (unsigned short)0;
    }
}

__device__ __forceinline__ void load_bq_ws(bf16x8 (&bq)[5], const unsigned short* kybase) {
    #pragma unroll
    for (int q = 0; q < 5; ++q)
        bq[q] = *(const bf16x8*)(kybase + q*512);
}

__device__ __forceinline__ void load_bq_fb(bf16x8 (&bq)[5], const unsigned short* s_w16,
                                           int ky, int hi, int ln) {
    #pragma unroll
    for (int q = 0; q < 5; ++q) {
        union { bf16x8 v; unsigned short s[8]; } u;
        #pragma unroll
        for (int j = 0; j < 8; ++j) {
            int kx = 16*q + 8*hi + j - ln;
            u.s[j] = (kx >= 0 && kx < KK) ? s_w16[ky*40 + kx] : (unsigned short)0;
        }
        bq[q] = u.v;
    }
}

#define MFMA_(T,Q) T = __builtin_amdgcn_mfma_f32_32x32x16_bf16(af, bq[Q], T, 0, 0, 0)

template<int NT>
__device__ __forceinline__ void compute_ky(const unsigned short* rp, const bf16x8 (&bq)[5],
                                           f32x16& A0, f32x16& A1)
{
    bf16x8 af;
#define LDC(c) af = *(const bf16x8*)(rp + 16*(c))
    if constexpr (NT == 2) {
        LDC(0); MFMA_(A0,0);
        LDC(1); MFMA_(A0,1);
        LDC(2); MFMA_(A0,2); MFMA_(A1,0);
        LDC(3); MFMA_(A0,3); MFMA_(A1,1);
        LDC(4); MFMA_(A0,4); MFMA_(A1,2);
        LDC(5); MFMA_(A1,3);
        LDC(6); MFMA_(A1,4);
    } else {
        LDC(0); MFMA_(A0,0);
        LDC(1); MFMA_(A0,1);
        LDC(2); MFMA_(A0,2);
        LDC(3); MFMA_(A0,3);
        LDC(4); MFMA_(A0,4);
    }
#undef LDC
}

template<bool FROM_WS, int NT>
__device__ __forceinline__ void kloop(
    const unsigned short* base,              // &s_band[ln*BSTR + 64w + 8hi]
    const unsigned short* fb,                // ws frag base (incl. lane off) or s_w16
    int hi, int ln, f32x16& A0, f32x16& A1)
{
    bf16x8 bqA[5], bqB[5];
    if constexpr (FROM_WS) load_bq_ws(bqA, fb); else load_bq_fb(bqA, fb, 0, hi, ln);
    for (int ky = 0; ky < KK; ky += 2) {
        if (ky + 1 < KK) {
            if constexpr (FROM_WS) load_bq_ws(bqB, fb + (size_t)(ky + 1)*FRAGS);
            else load_bq_fb(bqB, fb, ky + 1, hi, ln);
        }
        __builtin_amdgcn_s_setprio(1);
        compute_ky<NT>(base + ky*BSTR, bqA, A0, A1);
        __builtin_amdgcn_s_setprio(0);
        if (ky + 1 >= KK) break;
        if (ky + 2 < KK) {
            if constexpr (FROM_WS) load_bq_ws(bqA, fb + (size_t)(ky + 2)*FRAGS);
            else load_bq_fb(bqA, fb, ky + 2, hi, ln);
        }
        __builtin_amdgcn_s_setprio(1);
        compute_ky<NT>(base + (ky + 1)*BSTR, bqB, A0, A1);
        __builtin_amdgcn_s_setprio(0);
    }
}

template<bool FROM_WS>
__global__ __launch_bounds__(256, 4) void optics_mfma(
    const float* __restrict__ batch,
    const float* __restrict__ psf,
    const unsigned short* __restrict__ tt,
    const int* __restrict__ params,
    const float* __restrict__ weights,
    float* __restrict__ out)
{
    __shared__ __align__(16) unsigned short s_band[BROWS*BSTR + 16]; // 35,936 B
    __shared__ __align__(16) unsigned short s_w16[FROM_WS ? 8 : KK*40];

    const int tid = threadIdx.x;
    const int yband = blockIdx.x;            // 0..6
    const int plane = blockIdx.y;            // 0..191
    const int b = plane / CC, c = plane - b*CC;
    const int y0 = yband * BM;
    const int p = params[b];

    // --- stage reflect-padded band, fp32 -> bf16 ---
    const float* src = batch + (size_t)plane * PLANE;
    // interior: gx 0..223 as 56 aligned float4 groups -> cols 18..241
    for (int i = tid; i < BROWS*56; i += 256) {
        int r = i / 56, g = i - r*56;
        int gy = y0 + r - PP;
        gy = gy < 0 ? -gy : (gy >= HH ? 2*HH - 2 - gy : gy);
        float4 v = *(const float4*)&src[gy*WW + 4*g];
        unsigned int lo  = f2bf(v.x) | ((unsigned int)f2bf(v.y) << 16);
        unsigned int hi2 = f2bf(v.z) | ((unsigned int)f2bf(v.w) << 16);
        unsigned int* d = (unsigned int*)&s_band[r*BSTR + PP + 4*g];
        d[0] = lo; d[1] = hi2;
    }
    // edges: cols 0..17 (left reflect), 242..259 (right reflect), 260..263 (zero)
    for (int i = tid; i < BROWS*40; i += 256) {
        int r = i / 40, e = i - r*40;
        int col = e < PP ? e : (224 + e);     // e=18..39 -> col 242..263
        unsigned short v = 0;
        if (col < 260) {
            int gy = y0 + r - PP;
            gy = gy < 0 ? -gy : (gy >= HH ? 2*HH - 2 - gy : gy);
            int gx = col - PP;
            gx = gx < 0 ? -gx : (gx >= WW ? 2*WW - 2 - gx : gx);
            v = f2bf(src[gy*WW + gx]);
        }
        s_band[r*BSTR + col] = v;
    }
    if (tid < 16) s_band[BROWS*BSTR + tid] = 0;   // guard tail (tile-6 overrun, B=0 there)
    if constexpr (!FROM_WS) {
        const float* ksrc = psf + (size_t)((p*5 + 2)*CC + c) * (KK*KK);
        for (int i = tid; i < KK*KK; i += 256) {
            int ky_ = i / KK, kx_ = i - ky_*KK;
            s_w16[ky_*40 + kx_] = f2bf(ksrc[i]);
        }
    }
    __syncthreads();     // the ONLY barrier

    const int lane = tid & 63;
    const int w    = tid >> 6;               // wave 0..3: tiles {0,1}{2,3}{4,5}{6}
    const int ln   = lane & 31;
    const int hi   = lane >> 5;

    const unsigned short* fb;
    if constexpr (FROM_WS)
        fb = tt + (size_t)((p*CC + c)*KK)*FRAGS + hi*256 + ln*8;
    else
        fb = s_w16;
    // tile pair {2w, 2w+1} starts at column 64*w (was 32*w: the round-6 bug)
    const unsigned short* base = &s_band[ln*BSTR + 64*w + 8*hi];

    f32x16 A0 = {0,0,0,0, 0,0,0,0, 0,0,0,0, 0,0,0,0};
    f32x16 A1 = A0;

    if (w < 3) kloop<FROM_WS, 2>(base, fb, hi, ln, A0, A1);
    else       kloop<FROM_WS, 1>(base, fb, hi, ln, A0, A1);

    // --- epilogue: blend + store ---
    const float wt = weights[b];
    const float w1 = 1.0f - wt;
    float* dst = out + (size_t)plane * PLANE;
#define EPI(ACC, GT) { \
    _Pragma("unroll") \
    for (int r = 0; r < 16; ++r) { \
        const int rowL = (r & 3) + 8*(r >> 2) + 4*hi; \
        const int yo = y0 + rowL; \
        const int xo = 32*(GT) + ln; \
        const float orig = bf2f(s_band[(rowL + PP)*BSTR + xo + PP]); \
        dst[yo*WW + xo] = w1*orig + wt*ACC[r]; \
    } }
    EPI(A0, 2*w)
    if (w < 3) EPI(A1, 2*w + 1)
#undef EPI
}

__global__ void copy_targets(const int* __restrict__ t, float* __restrict__ out) {
    int i = threadIdx.x;
    if (i < BB) out[i] = (float)t[i];
}

extern "C" void kernel_launch(void* const* d_in, const int* in_sizes, int n_in,
                              void* d_out, int out_size, void* d_ws, size_t ws_size,
                              hipStream_t stream) {
    const float* batch   = (const float*)d_in[0];
    const int*   targets = (const int*)d_in[1];
    const float* psf     = (const float*)d_in[2];
    const int*   params  = (const int*)d_in[3];
    const float* weights = (const float*)d_in[4];
    float* out = (float*)d_out;
    unsigned short* tt = (unsigned short*)d_ws;

    const size_t need = (size_t)NTT * FRAGS * sizeof(unsigned short);  // ~4.55 MB
    dim3 grid(HH / BM, BB*CC);                // 7 x 192 = 1344 blocks

    if (ws_size >= need) {
        build_frags<<<NTT, 256, 0, stream>>>(psf, tt);
        optics_mfma<true><<<grid, 256, 0, stream>>>(batch, psf, tt, params, weights, out);
    } else {
        optics_mfma<false><<<grid, 256, 0, stream>>>(batch, psf, tt, params, weights, out);
    }
    copy_targets<<<1, 64, 0, stream>>>(targets, out + (size_t)BB*CC*PLANE);
}